// Round 12
// baseline (395.724 us; speedup 1.0000x reference)
//
#include <hip/hip_runtime.h>
#include <hip/hip_bf16.h>
#include <hip/hip_cooperative_groups.h>

namespace cg = cooperative_groups;

#define NSP 4096   // spatial points = 16*16*16
#define QSC2 0.25503486f   // log2(e)/sqrt(32): folded so softmax uses exp2

typedef __attribute__((ext_vector_type(8))) short bf16x8;
typedef __attribute__((ext_vector_type(4))) float f32x4;
typedef __attribute__((ext_vector_type(16))) float f32x16;

__device__ __forceinline__ unsigned short f2bf(float f){
  union{float f;unsigned int u;}c; c.f=f;
  unsigned int r = c.u + 0x7fffu + ((c.u>>16)&1u);
  return (unsigned short)(r>>16);
}
__device__ __forceinline__ unsigned int pk2(float a, float b){
  __hip_bfloat162 p = __float22bfloat162_rn(make_float2(a, b));
  unsigned int r; __builtin_memcpy(&r, &p, 4); return r;
}
__device__ __forceinline__ ushort4 pk4(float a, float b, float c, float d){
  union { ushort4 u4; uint2 u2; } u;
  u.u2.x = pk2(a, b); u.u2.y = pk2(c, d);
  return u.u4;
}
__device__ __forceinline__ float bfu2f(unsigned short u){
  union { unsigned int i; float f; } c; c.i = ((unsigned int)u) << 16; return c.f;
}

struct FParams {
  const float* x; const float* wdw;
  const float* wqkv; const float* bqkv;
  const float* wproj; const float* bproj;
  unsigned short* ybn; unsigned short* qb; unsigned short* kb; unsigned short* vbt;
  unsigned short* opb; float* lp; float2* stats;
  float* out; int nz; int ktlen;
};

// ---------------------------------------------------------------------------
// Fused cooperative kernel: 512 blocks x 256 threads, 4 grid syncs.
// LDS is a 67840 B arena re-cast per stage (max = QKV stage).
// ---------------------------------------------------------------------------
__global__ __launch_bounds__(256) void k_fused(FParams p)
{
  __shared__ __align__(16) char smem[67840];
  cg::grid_group gg = cg::this_grid();
  const int tid = threadIdx.x;
  const int bid = blockIdx.x;
  const int w = tid >> 6, lane = tid & 63, quad = lane >> 4, cc = lane & 15;

  // ===== Stage A1: dwconv (half channel per block), partial stats =====
  float a8[8];
  {
    float* xs  = (float*)smem;                 // 4096 f
    float* wsh = (float*)(smem + 16384);       // 27 f
    float* rs  = (float*)(smem + 16512);
    float* rq  = (float*)(smem + 16544);
    const int c = bid >> 1, half = bid & 1;
    const float* xc = p.x + (size_t)c * NSP;
    #pragma unroll
    for (int i = 0; i < 4; i++)
      *(float4*)&xs[(i*256 + tid)*4] = ((const float4*)xc)[i*256 + tid];
    if (tid < 27) wsh[tid] = p.wdw[c*27 + tid];
    __syncthreads();

    const int h = half*8 + (tid >> 5), ww0 = (tid >> 1) & 15, d0 = (tid & 1) * 8;
    #pragma unroll
    for (int j = 0; j < 8; j++) a8[j] = 0.f;
    #pragma unroll
    for (int kh = 0; kh < 3; kh++){
      const int hh = h + kh - 1;
      if ((unsigned)hh >= 16u) continue;
      #pragma unroll
      for (int kw = 0; kw < 3; kw++){
        const int ww = ww0 + kw - 1;
        if ((unsigned)ww >= 16u) continue;
        const float* rowp = &xs[((hh << 4) + ww) << 4];
        float win[10];
        const float4 c0 = *(const float4*)&rowp[d0];
        const float4 c1 = *(const float4*)&rowp[d0 + 4];
        win[1] = c0.x; win[2] = c0.y; win[3] = c0.z; win[4] = c0.w;
        win[5] = c1.x; win[6] = c1.y; win[7] = c1.z; win[8] = c1.w;
        win[0] = d0 ? rowp[7] : 0.f;
        win[9] = d0 ? 0.f : rowp[8];
        #pragma unroll
        for (int kd = 0; kd < 3; kd++){
          const float wv = wsh[kh*9 + kw*3 + kd];
          #pragma unroll
          for (int j = 0; j < 8; j++) a8[j] += wv * win[j + kd];
        }
      }
    }
    float sum = 0.f, sumsq = 0.f;
    #pragma unroll
    for (int j = 0; j < 8; j++){ sum += a8[j]; sumsq += a8[j]*a8[j]; }
    #pragma unroll
    for (int off = 32; off > 0; off >>= 1){
      sum   += __shfl_down(sum, off, 64);
      sumsq += __shfl_down(sumsq, off, 64);
    }
    if (lane == 0){ rs[w] = sum; rq[w] = sumsq; }
    __syncthreads();
    if (tid == 0)
      p.stats[bid] = make_float2(rs[0]+rs[1]+rs[2]+rs[3], rq[0]+rq[1]+rq[2]+rq[3]);
  }
  gg.sync();

  // ===== Stage A2: normalize + write ybn (conv accum still in registers) ===
  {
    const int c = bid >> 1, half = bid & 1;
    const float2 s0 = p.stats[bid & ~1], s1 = p.stats[bid | 1];
    const float mean = (s0.x + s1.x) * (1.f/4096.f);
    const float var  = (s0.y + s1.y) * (1.f/4096.f) - mean*mean;
    const float rinv = rsqrtf(var + 1e-5f);
    const int h = half*8 + (tid >> 5), ww0 = (tid >> 1) & 15, d0 = (tid & 1) * 8;
    unsigned short* yo = p.ybn + (size_t)c * NSP + (h << 8) + (ww0 << 4) + d0;
    *(ushort4*)yo =
        pk4((a8[0]-mean)*rinv, (a8[1]-mean)*rinv, (a8[2]-mean)*rinv, (a8[3]-mean)*rinv);
    *(ushort4*)(yo + 4) =
        pk4((a8[4]-mean)*rinv, (a8[5]-mean)*rinv, (a8[6]-mean)*rinv, (a8[7]-mean)*rinv);
  }
  gg.sync();

  // ===== Stage B: QKV GEMM. n-tile per 8 blocks; Ys staged once/block. =====
  {
    unsigned short (*Ys)[264] = (unsigned short (*)[264])smem;            // 33792 B
    unsigned short (*Wb)[264] = (unsigned short (*)[264])(smem + 33792);  // 33792 B
    float* bsh = (float*)(smem + 67584);                                  // 256 B
    const int nt = bid >> 3, oslot = bid & 7;
    const int n0 = nt * 64;
    { // transpose-stage Y tile [n][c]
      const int cl = tid >> 4, n4 = (tid & 15) * 4;
      #pragma unroll
      for (int i = 0; i < 16; i++){
        const int c = cl*16 + i;
        const ushort4 v = *(const ushort4*)(p.ybn + (size_t)c * NSP + n0 + n4);
        Ys[n4+0][c] = v.x; Ys[n4+1][c] = v.y; Ys[n4+2][c] = v.z; Ys[n4+3][c] = v.w;
      }
    }
    const int numo = (oslot < 4) ? 2 : 1;
    for (int oi = 0; oi < numo; oi++){
      const int o0 = (oslot + oi*8) * 64;
      __syncthreads();   // Ys staged / prior Wb reads done
      { // stage W tile bf16 + bias
        const int row = tid & 63, part = tid >> 6;
        const float* src = p.wqkv + (size_t)(o0 + row) * 256 + part * 64;
        unsigned short* dst = &Wb[row][part*64];
        #pragma unroll
        for (int j = 0; j < 8; j++){
          const float4 a = ((const float4*)src)[2*j];
          const float4 b = ((const float4*)src)[2*j+1];
          *(ushort4*)&dst[j*8]     = pk4(a.x, a.y, a.z, a.w);
          *(ushort4*)&dst[j*8 + 4] = pk4(b.x, b.y, b.z, b.w);
        }
        if (tid < 64) bsh[tid] = p.bqkv[o0 + tid];
      }
      __syncthreads();

      const int nbase = n0 + w*16;
      const bool isv = (o0 >= 512);
      f32x4 acc[4] = {};
      #pragma unroll
      for (int k = 0; k < 8; k++){
        const bf16x8 y0 = *(const bf16x8*)&Ys[w*16 + cc][k*32 + quad*8];
        #pragma unroll
        for (int os = 0; os < 4; os++){
          const bf16x8 wf = *(const bf16x8*)&Wb[os*16 + cc][k*32 + quad*8];
          if (!isv) acc[os] = __builtin_amdgcn_mfma_f32_16x16x32_bf16(wf, y0, acc[os], 0, 0, 0);
          else      acc[os] = __builtin_amdgcn_mfma_f32_16x16x32_bf16(y0, wf, acc[os], 0, 0, 0);
        }
      }
      if (!isv){
        #pragma unroll
        for (int os = 0; os < 4; os++){
          const int obase = o0 + os*16 + quad*4;
          const int g = obase >> 8, hh = (obase >> 5) & 7, dd0 = obase & 31;
          const int n = nbase + cc;
          unsigned short* dst = (g == 0) ? p.qb : p.kb;
          const float sc = (g == 0) ? QSC2 : 1.f;
          const int bb = os*16 + quad*4;
          *(ushort4*)&dst[((size_t)hh * NSP + n) * 32 + dd0] =
              pk4((acc[os][0] + bsh[bb+0]) * sc, (acc[os][1] + bsh[bb+1]) * sc,
                  (acc[os][2] + bsh[bb+2]) * sc, (acc[os][3] + bsh[bb+3]) * sc);
        }
      } else {
        #pragma unroll
        for (int os = 0; os < 4; os++){
          const int orow = o0 - 512 + os*16 + cc;   // = h*32+dd
          const float bias = bsh[os*16 + cc];
          const int n4 = nbase + quad*4;
          *(ushort4*)&p.vbt[(size_t)orow * NSP + n4] =
              pk4(acc[os][0] + bias, acc[os][1] + bias, acc[os][2] + bias, acc[os][3] + bias);
        }
      }
    }
  }
  gg.sync();

  // ===== Stage C: flash attention (32x32x16), tasks strided over grid =====
  {
    unsigned short (*ks)[40]  = (unsigned short (*)[40])smem;            // 5120 B
    unsigned short (*vsT)[72] = (unsigned short (*)[72])(smem + 5120);   // 4608 B
    unsigned short (*pst)[72] = (unsigned short (*)[72])(smem + 9728);   // 18432 B
    const int lq = lane & 31, lb = lane >> 5;
    const int krow = tid >> 2, kseg = (tid & 3) * 8;
    const int vrow = tid >> 3, vseg = (tid & 7) * 8;
    const int ntask = p.nz << 8;

    for (int t = bid; t < ntask; t += 512){
      const int qx = t & 31, h = (t >> 5) & 7, z = t >> 8;
      const int q0 = qx * 128;
      const int qg = q0 + w*32 + lq;
      const bf16x8 qf0 = *(const bf16x8*)(p.qb + ((size_t)(h*NSP + qg))*32 + lb*8);
      const bf16x8 qf1 = *(const bf16x8*)(p.qb + ((size_t)(h*NSP + qg))*32 + 16 + lb*8);
      const unsigned short* kbase = p.kb  + (size_t)h * NSP * 32;
      const unsigned short* vbase = p.vbt + (size_t)h * 32 * NSP;

      f32x16 oacc = {};
      float lsum = 0.f;
      const int kt0 = z * p.ktlen;
      const int iters = p.ktlen >> 6;
      __syncthreads();   // protect LDS arena from previous use

      for (int it = 0; it < iters; it++){
        const int kt = kt0 + it * 64;
        *(uint4*)&ks[krow][kseg]  = *(const uint4*)(kbase + (size_t)(kt + krow) * 32 + kseg);
        *(uint4*)&vsT[vrow][vseg] = *(const uint4*)(vbase + (size_t)vrow * NSP + kt + vseg);
        __syncthreads();

        #pragma unroll
        for (int t2 = 0; t2 < 2; t2++){
          const bf16x8 af0 = *(const bf16x8*)&ks[t2*32 + lq][lb*8];
          const bf16x8 af1 = *(const bf16x8*)&ks[t2*32 + lq][16 + lb*8];
          f32x16 sa = {};
          sa = __builtin_amdgcn_mfma_f32_32x32x16_bf16(af0, qf0, sa, 0, 0, 0);
          sa = __builtin_amdgcn_mfma_f32_32x32x16_bf16(af1, qf1, sa, 0, 0, 0);
          #pragma unroll
          for (int g = 0; g < 4; g++){
            const float p0 = __builtin_amdgcn_exp2f(sa[g*4+0]);
            const float p1 = __builtin_amdgcn_exp2f(sa[g*4+1]);
            const float p2 = __builtin_amdgcn_exp2f(sa[g*4+2]);
            const float p3 = __builtin_amdgcn_exp2f(sa[g*4+3]);
            lsum += (p0 + p1) + (p2 + p3);
            *(ushort4*)&pst[w*32 + lq][t2*32 + g*8 + lb*4] = pk4(p0, p1, p2, p3);
          }
        }
        #pragma unroll
        for (int ck = 0; ck < 4; ck++){
          const bf16x8 vf = *(const bf16x8*)&vsT[lq]       [ck*16 + lb*8];
          const bf16x8 pf = *(const bf16x8*)&pst[w*32 + lq][ck*16 + lb*8];
          oacc = __builtin_amdgcn_mfma_f32_32x32x16_bf16(vf, pf, oacc, 0, 0, 0);
        }
        __syncthreads();
      }

      lsum += __shfl_xor(lsum, 32, 64);
      unsigned short* dst = p.opb + ((size_t)z * NSP + qg) * 256 + h*32;
      #pragma unroll
      for (int g = 0; g < 4; g++){
        *(ushort4*)(dst + g*8 + lb*4) =
            pk4(oacc[g*4+0], oacc[g*4+1], oacc[g*4+2], oacc[g*4+3]);
      }
      if (lb == 0) p.lp[((size_t)z * 8 + h) * NSP + qg] = lsum;
    }
  }
  gg.sync();

  // ===== Stage D: combine + output projection (one 32o x 64n tile/block) ===
  {
    unsigned short (*Wb)[264] = (unsigned short (*)[264])smem;   // 16896 B
    const int n0 = (bid & 63) * 64, o0 = (bid >> 6) * 32;
    {
      const int row = tid & 31, part = tid >> 5;
      const float* src = p.wproj + (size_t)(o0 + row) * 256 + part * 32;
      unsigned short* dst = &Wb[row][part*32];
      #pragma unroll
      for (int j = 0; j < 4; j++){
        const float4 a = ((const float4*)src)[2*j];
        const float4 b = ((const float4*)src)[2*j+1];
        *(ushort4*)&dst[j*8]     = pk4(a.x, a.y, a.z, a.w);
        *(ushort4*)&dst[j*8 + 4] = pk4(b.x, b.y, b.z, b.w);
      }
    }
    __syncthreads();

    const int nbase = n0 + w*16;
    const int nr = nbase + cc;
    f32x4 acc[2] = {};
    #pragma unroll
    for (int k = 0; k < 8; k++){
      float lt = 0.f;
      float s[8] = {};
      for (int z = 0; z < p.nz; z++){
        lt += p.lp[((size_t)z*8 + k) * NSP + nr];
        union { uint4 q; unsigned short u[8]; } v;
        v.q = *(const uint4*)(p.opb + ((size_t)z * NSP + nr) * 256 + k*32 + quad*8);
        #pragma unroll
        for (int j = 0; j < 8; j++) s[j] += bfu2f(v.u[j]);
      }
      const float r = 1.f / lt;
      union { bf16x8 v; ushort4 u[2]; } yb;
      yb.u[0] = pk4(s[0]*r, s[1]*r, s[2]*r, s[3]*r);
      yb.u[1] = pk4(s[4]*r, s[5]*r, s[6]*r, s[7]*r);
      #pragma unroll
      for (int os = 0; os < 2; os++){
        const bf16x8 wf = *(const bf16x8*)&Wb[os*16 + cc][k*32 + quad*8];
        acc[os] = __builtin_amdgcn_mfma_f32_16x16x32_bf16(yb.v, wf, acc[os], 0, 0, 0);
      }
    }
    #pragma unroll
    for (int os = 0; os < 2; os++){
      const int o = o0 + os*16 + cc;
      const float bias = p.bproj[o];
      const int n4 = nbase + quad*4;
      *(float4*)&p.out[(size_t)o * NSP + n4] =
          make_float4(acc[os][0] + bias, acc[os][1] + bias,
                      acc[os][2] + bias, acc[os][3] + bias);
    }
  }
}

// ===========================================================================
// Fallback path: round-11 kernels (used only if cooperative launch fails).
// ===========================================================================
__global__ __launch_bounds__(1024) void k_dwconv(
    const float* __restrict__ x, const float* __restrict__ wdw,
    unsigned short* __restrict__ ybn)
{
  const int c = blockIdx.x;
  const int tid = threadIdx.x;
  __shared__ float xs[4096];
  __shared__ float wsh[27];
  __shared__ float rs[16], rq[16];
  const float* xc = x + (size_t)c * NSP;
  *(float4*)&xs[tid*4] = ((const float4*)xc)[tid];
  if (tid < 27) wsh[tid] = wdw[c*27 + tid];
  __syncthreads();
  const int h = tid >> 6, w = (tid >> 2) & 15, d0 = (tid & 3) * 4;
  float acc[4] = {};
  #pragma unroll
  for (int kh = 0; kh < 3; kh++){
    const int hh = h + kh - 1;
    if ((unsigned)hh >= 16u) continue;
    #pragma unroll
    for (int kw = 0; kw < 3; kw++){
      const int ww = w + kw - 1;
      if ((unsigned)ww >= 16u) continue;
      const float* rowp = &xs[((hh << 4) + ww) << 4];
      float win[6];
      const float4 c0 = *(const float4*)&rowp[d0];
      win[1] = c0.x; win[2] = c0.y; win[3] = c0.z; win[4] = c0.w;
      win[0] = d0        ? rowp[d0 - 1] : 0.f;
      win[5] = (d0 < 12) ? rowp[d0 + 4] : 0.f;
      #pragma unroll
      for (int kd = 0; kd < 3; kd++){
        const float wv = wsh[kh*9 + kw*3 + kd];
        #pragma unroll
        for (int j = 0; j < 4; j++) acc[j] += wv * win[j + kd];
      }
    }
  }
  float sum = 0.f, sumsq = 0.f;
  #pragma unroll
  for (int j = 0; j < 4; j++){ sum += acc[j]; sumsq += acc[j]*acc[j]; }
  #pragma unroll
  for (int off = 32; off > 0; off >>= 1){
    sum   += __shfl_down(sum, off, 64);
    sumsq += __shfl_down(sumsq, off, 64);
  }
  const int wid = tid >> 6, lane = tid & 63;
  if (lane == 0){ rs[wid] = sum; rq[wid] = sumsq; }
  __syncthreads();
  float ts = 0.f, tq = 0.f;
  #pragma unroll
  for (int i = 0; i < 16; i++){ ts += rs[i]; tq += rq[i]; }
  const float mean = ts * (1.f/4096.f);
  const float var  = tq * (1.f/4096.f) - mean*mean;
  const float rinv = rsqrtf(var + 1e-5f);
  *(ushort4*)(ybn + (size_t)c * NSP + tid*4) =
      pk4((acc[0]-mean)*rinv, (acc[1]-mean)*rinv, (acc[2]-mean)*rinv, (acc[3]-mean)*rinv);
}

__global__ __launch_bounds__(256) void k_qkv(
    const float* __restrict__ wqkv, const float* __restrict__ bqkv,
    const unsigned short* __restrict__ ybn,
    unsigned short* __restrict__ qb, unsigned short* __restrict__ kb,
    unsigned short* __restrict__ vbt)
{
  __shared__ unsigned short Wb[64][264];
  __shared__ unsigned short Ys[64][264];
  __shared__ float bsh[64];
  const int tid = threadIdx.x;
  const int o0 = blockIdx.y * 64;
  const int n0 = blockIdx.x * 64;
  {
    const int row = tid & 63, part = tid >> 6;
    const float* src = wqkv + (size_t)(o0 + row) * 256 + part * 64;
    unsigned short* dst = &Wb[row][part*64];
    #pragma unroll
    for (int j = 0; j < 8; j++){
      const float4 a = ((const float4*)src)[2*j];
      const float4 b = ((const float4*)src)[2*j+1];
      *(ushort4*)&dst[j*8]     = pk4(a.x, a.y, a.z, a.w);
      *(ushort4*)&dst[j*8 + 4] = pk4(b.x, b.y, b.z, b.w);
    }
    if (tid < 64) bsh[tid] = bqkv[o0 + tid];
  }
  {
    const int cl = tid >> 4, n4 = (tid & 15) * 4;
    #pragma unroll
    for (int i = 0; i < 16; i++){
      const int c = cl * 16 + i;
      const ushort4 v = *(const ushort4*)(ybn + (size_t)c * NSP + n0 + n4);
      Ys[n4+0][c] = v.x; Ys[n4+1][c] = v.y; Ys[n4+2][c] = v.z; Ys[n4+3][c] = v.w;
    }
  }
  __syncthreads();
  const int w = tid >> 6, lane = tid & 63, quad = lane >> 4, cc = lane & 15;
  const int nbase = n0 + w*16;
  const bool isv = (o0 >= 512);
  f32x4 acc[4] = {};
  #pragma unroll
  for (int k = 0; k < 8; k++){
    const bf16x8 y0 = *(const bf16x8*)&Ys[w*16 + cc][k*32 + quad*8];
    #pragma unroll
    for (int os = 0; os < 4; os++){
      const bf16x8 wf = *(const bf16x8*)&Wb[os*16 + cc][k*32 + quad*8];
      if (!isv) acc[os] = __builtin_amdgcn_mfma_f32_16x16x32_bf16(wf, y0, acc[os], 0, 0, 0);
      else      acc[os] = __builtin_amdgcn_mfma_f32_16x16x32_bf16(y0, wf, acc[os], 0, 0, 0);
    }
  }
  if (!isv){
    #pragma unroll
    for (int os = 0; os < 4; os++){
      const int obase = o0 + os*16 + quad*4;
      const int g = obase >> 8, hh = (obase >> 5) & 7, dd0 = obase & 31;
      const int n = nbase + cc;
      unsigned short* dst = (g == 0) ? qb : kb;
      const float sc = (g == 0) ? QSC2 : 1.f;
      const int bb = os*16 + quad*4;
      *(ushort4*)&dst[((size_t)hh * NSP + n) * 32 + dd0] =
          pk4((acc[os][0] + bsh[bb+0]) * sc, (acc[os][1] + bsh[bb+1]) * sc,
              (acc[os][2] + bsh[bb+2]) * sc, (acc[os][3] + bsh[bb+3]) * sc);
    }
  } else {
    #pragma unroll
    for (int os = 0; os < 4; os++){
      const int orow = o0 - 512 + os*16 + cc;
      const float bias = bsh[os*16 + cc];
      const int n4 = nbase + quad*4;
      *(ushort4*)&vbt[(size_t)orow * NSP + n4] =
          pk4(acc[os][0] + bias, acc[os][1] + bias, acc[os][2] + bias, acc[os][3] + bias);
    }
  }
}

__global__ __launch_bounds__(256) void k_attn(
    const unsigned short* __restrict__ qb,
    const unsigned short* __restrict__ kb,
    const unsigned short* __restrict__ vbt,
    unsigned short* __restrict__ opb, float* __restrict__ lp, int ktlen)
{
  const int h = blockIdx.y, q0 = blockIdx.x * 128, z = blockIdx.z;
  const int tid = threadIdx.x;
  const int w = tid >> 6, l = tid & 63;
  const int lq = l & 31, lb = l >> 5;
  __shared__ unsigned short ks [64][40];
  __shared__ unsigned short vsT[32][72];
  __shared__ unsigned short pst[128][72];
  const int qg = q0 + w*32 + lq;
  const bf16x8 qf0 = *(const bf16x8*)(qb + ((size_t)(h*NSP + qg))*32 + lb*8);
  const bf16x8 qf1 = *(const bf16x8*)(qb + ((size_t)(h*NSP + qg))*32 + 16 + lb*8);
  const unsigned short* kbase = kb  + (size_t)h * NSP * 32;
  const unsigned short* vbase = vbt + (size_t)h * 32 * NSP;
  f32x16 oacc = {};
  float lsum = 0.f;
  const int kt0 = z * ktlen;
  const int krow = tid >> 2, kseg = (tid & 3) * 8;
  const int vrow = tid >> 3, vseg = (tid & 7) * 8;
  const int iters = ktlen >> 6;
  for (int it = 0; it < iters; it++){
    const int kt = kt0 + it * 64;
    *(uint4*)&ks[krow][kseg]  = *(const uint4*)(kbase + (size_t)(kt + krow) * 32 + kseg);
    *(uint4*)&vsT[vrow][vseg] = *(const uint4*)(vbase + (size_t)vrow * NSP + kt + vseg);
    __syncthreads();
    #pragma unroll
    for (int t2 = 0; t2 < 2; t2++){
      const bf16x8 af0 = *(const bf16x8*)&ks[t2*32 + lq][lb*8];
      const bf16x8 af1 = *(const bf16x8*)&ks[t2*32 + lq][16 + lb*8];
      f32x16 sa = {};
      sa = __builtin_amdgcn_mfma_f32_32x32x16_bf16(af0, qf0, sa, 0, 0, 0);
      sa = __builtin_amdgcn_mfma_f32_32x32x16_bf16(af1, qf1, sa, 0, 0, 0);
      #pragma unroll
      for (int g = 0; g < 4; g++){
        const float p0 = __builtin_amdgcn_exp2f(sa[g*4+0]);
        const float p1 = __builtin_amdgcn_exp2f(sa[g*4+1]);
        const float p2 = __builtin_amdgcn_exp2f(sa[g*4+2]);
        const float p3 = __builtin_amdgcn_exp2f(sa[g*4+3]);
        lsum += (p0 + p1) + (p2 + p3);
        *(ushort4*)&pst[w*32 + lq][t2*32 + g*8 + lb*4] = pk4(p0, p1, p2, p3);
      }
    }
    #pragma unroll
    for (int ck = 0; ck < 4; ck++){
      const bf16x8 vf = *(const bf16x8*)&vsT[lq]       [ck*16 + lb*8];
      const bf16x8 pf = *(const bf16x8*)&pst[w*32 + lq][ck*16 + lb*8];
      oacc = __builtin_amdgcn_mfma_f32_32x32x16_bf16(vf, pf, oacc, 0, 0, 0);
    }
    __syncthreads();
  }
  lsum += __shfl_xor(lsum, 32, 64);
  unsigned short* dst = opb + ((size_t)z * NSP + qg) * 256 + h*32;
  #pragma unroll
  for (int g = 0; g < 4; g++){
    *(ushort4*)(dst + g*8 + lb*4) =
        pk4(oacc[g*4+0], oacc[g*4+1], oacc[g*4+2], oacc[g*4+3]);
  }
  if (lb == 0) lp[((size_t)z * 8 + h) * NSP + qg] = lsum;
}

__global__ __launch_bounds__(256) void k_proj(
    const float* __restrict__ wproj, const float* __restrict__ bproj,
    const unsigned short* __restrict__ opb, const float* __restrict__ lp,
    float* __restrict__ out, int nz)
{
  __shared__ unsigned short Wb[32][264];
  const int tid = threadIdx.x;
  const int o0 = blockIdx.y * 32;
  const int n0 = blockIdx.x * 64;
  {
    const int row = tid & 31, part = tid >> 5;
    const float* src = wproj + (size_t)(o0 + row) * 256 + part * 32;
    unsigned short* dst = &Wb[row][part*32];
    #pragma unroll
    for (int j = 0; j < 4; j++){
      const float4 a = ((const float4*)src)[2*j];
      const float4 b = ((const float4*)src)[2*j+1];
      *(ushort4*)&dst[j*8]     = pk4(a.x, a.y, a.z, a.w);
      *(ushort4*)&dst[j*8 + 4] = pk4(b.x, b.y, b.z, b.w);
    }
  }
  __syncthreads();
  const int w = tid >> 6, lane = tid & 63, quad = lane >> 4, cc = lane & 15;
  const int nbase = n0 + w*16;
  const int nr = nbase + cc;
  f32x4 acc[2] = {};
  #pragma unroll
  for (int k = 0; k < 8; k++){
    float lt = 0.f;
    float s[8] = {};
    for (int z = 0; z < nz; z++){
      lt += lp[((size_t)z*8 + k) * NSP + nr];
      union { uint4 q; unsigned short u[8]; } v;
      v.q = *(const uint4*)(opb + ((size_t)z * NSP + nr) * 256 + k*32 + quad*8);
      #pragma unroll
      for (int j = 0; j < 8; j++) s[j] += bfu2f(v.u[j]);
    }
    const float r = 1.f / lt;
    union { bf16x8 v; ushort4 u[2]; } yb;
    yb.u[0] = pk4(s[0]*r, s[1]*r, s[2]*r, s[3]*r);
    yb.u[1] = pk4(s[4]*r, s[5]*r, s[6]*r, s[7]*r);
    #pragma unroll
    for (int os = 0; os < 2; os++){
      const bf16x8 wf = *(const bf16x8*)&Wb[os*16 + cc][k*32 + quad*8];
      acc[os] = __builtin_amdgcn_mfma_f32_16x16x32_bf16(yb.v, wf, acc[os], 0, 0, 0);
    }
  }
  #pragma unroll
  for (int os = 0; os < 2; os++){
    const int o = o0 + os*16 + cc;
    const float bias = bproj[o];
    const int n4 = nbase + quad*4;
    *(float4*)&out[(size_t)o * NSP + n4] =
        make_float4(acc[os][0] + bias, acc[os][1] + bias,
                    acc[os][2] + bias, acc[os][3] + bias);
  }
}

// ---------------------------------------------------------------------------
extern "C" void kernel_launch(void* const* d_in, const int* in_sizes, int n_in,
                              void* d_out, int out_size, void* d_ws, size_t ws_size,
                              hipStream_t stream) {
  (void)in_sizes; (void)n_in; (void)out_size;
  const float* x     = (const float*)d_in[0];
  const float* wdw   = (const float*)d_in[1];
  const float* bdw   = (const float*)d_in[2];  (void)bdw; // cancels under InstanceNorm
  const float* wqkv  = (const float*)d_in[3];
  const float* bqkv  = (const float*)d_in[4];
  const float* wproj = (const float*)d_in[5];
  const float* bproj = (const float*)d_in[6];
  float* out = (float*)d_out;

  const int nz = (ws_size >= ((size_t)16 << 20)) ? 4 : 2;
  const int ktlen = NSP / nz;

  char* ws = (char*)d_ws;
  const size_t opB = (size_t)nz << 21;                    // nz * 2 MB
  unsigned short* opb = (unsigned short*)ws;              // [nz][n][256] bf16
  unsigned short* ybn = (unsigned short*)ws;              // 2 MB (dead before opb written)
  unsigned short* qb  = (unsigned short*)(ws + opB);      // 2 MB bf16 [h][n][32]
  unsigned short* kb  = (unsigned short*)(ws + opB + (2<<20));
  unsigned short* vbt = (unsigned short*)(ws + opB + (4<<20));
  float*          lp  = (float*)(ws + opB + (6<<20));     // nz*128 KB [z][h][n]
  float2*         stats = (float2*)(ws + opB + (6<<20) + ((size_t)nz << 17)); // 4 KB

  FParams hp;
  hp.x = x; hp.wdw = wdw; hp.wqkv = wqkv; hp.bqkv = bqkv;
  hp.wproj = wproj; hp.bproj = bproj;
  hp.ybn = ybn; hp.qb = qb; hp.kb = kb; hp.vbt = vbt;
  hp.opb = opb; hp.lp = lp; hp.stats = stats; hp.out = out;
  hp.nz = nz; hp.ktlen = ktlen;
  void* kargs[] = { (void*)&hp };

  hipError_t err = hipLaunchCooperativeKernel(
      (const void*)k_fused, dim3(512), dim3(256), kargs, 0, stream);
  if (err != hipSuccess){
    (void)hipGetLastError();   // clear, fall back to split kernels
    k_dwconv <<<dim3(256),       dim3(1024), 0, stream>>>(x, wdw, ybn);
    k_qkv    <<<dim3(64, 12),    dim3(256),  0, stream>>>(wqkv, bqkv, ybn, qb, kb, vbt);
    k_attn   <<<dim3(32, 8, nz), dim3(256),  0, stream>>>(qb, kb, vbt, opb, lp, ktlen);
    k_proj   <<<dim3(64, 8),     dim3(256),  0, stream>>>(wproj, bproj, opb, lp, out, nz);
  }
}

// Round 13
// 148.711 us; speedup vs baseline: 2.6610x; 2.6610x over previous
//
#include <hip/hip_runtime.h>
#include <hip/hip_bf16.h>

#define NSP 4096   // spatial points = 16*16*16
#define QSC2 0.25503486f   // log2(e)/sqrt(32): folded so softmax uses exp2

typedef __attribute__((ext_vector_type(8))) short bf16x8;
typedef __attribute__((ext_vector_type(4))) float f32x4;
typedef __attribute__((ext_vector_type(16))) float f32x16;

__device__ __forceinline__ unsigned short f2bf(float f){
  union{float f;unsigned int u;}c; c.f=f;
  unsigned int r = c.u + 0x7fffu + ((c.u>>16)&1u);
  return (unsigned short)(r>>16);
}
__device__ __forceinline__ unsigned int pk2(float a, float b){
  __hip_bfloat162 p = __float22bfloat162_rn(make_float2(a, b));
  unsigned int r; __builtin_memcpy(&r, &p, 4); return r;
}
__device__ __forceinline__ ushort4 pk4(float a, float b, float c, float d){
  union { ushort4 u4; uint2 u2; } u;
  u.u2.x = pk2(a, b); u.u2.y = pk2(c, d);
  return u.u4;
}
__device__ __forceinline__ float bfu2f(unsigned short u){
  union { unsigned int i; float f; } c; c.i = ((unsigned int)u) << 16; return c.f;
}

// ---------------------------------------------------------------------------
// Kernel 1: depthwise 3x3x3 conv + InstanceNorm -> normalized bf16 ybn[c][n].
// (b_dw dropped: cancels under InstanceNorm.) One block per channel, 1024
// threads, each owns a 4-wide d-strip.
// ---------------------------------------------------------------------------
__global__ __launch_bounds__(1024) void k_dwconv(
    const float* __restrict__ x,
    const float* __restrict__ wdw,
    unsigned short* __restrict__ ybn)
{
  const int c = blockIdx.x;
  const int tid = threadIdx.x;
  __shared__ float xs[4096];
  __shared__ float wsh[27];
  __shared__ float rs[16], rq[16];

  const float* xc = x + (size_t)c * NSP;
  *(float4*)&xs[tid*4] = ((const float4*)xc)[tid];
  if (tid < 27) wsh[tid] = wdw[c*27 + tid];
  __syncthreads();

  // strip: h = t>>6, w = (t>>2)&15, d0 = (t&3)*4
  const int h = tid >> 6, w = (tid >> 2) & 15, d0 = (tid & 3) * 4;
  float acc[4] = {};
  #pragma unroll
  for (int kh = 0; kh < 3; kh++){
    const int hh = h + kh - 1;
    if ((unsigned)hh >= 16u) continue;
    #pragma unroll
    for (int kw = 0; kw < 3; kw++){
      const int ww = w + kw - 1;
      if ((unsigned)ww >= 16u) continue;
      const float* rowp = &xs[((hh << 4) + ww) << 4];
      float win[6];
      const float4 c0 = *(const float4*)&rowp[d0];
      win[1] = c0.x; win[2] = c0.y; win[3] = c0.z; win[4] = c0.w;
      win[0] = d0        ? rowp[d0 - 1] : 0.f;   // global d = d0-1
      win[5] = (d0 < 12) ? rowp[d0 + 4] : 0.f;   // global d = d0+4
      #pragma unroll
      for (int kd = 0; kd < 3; kd++){
        const float wv = wsh[kh*9 + kw*3 + kd];
        #pragma unroll
        for (int j = 0; j < 4; j++) acc[j] += wv * win[j + kd];
      }
    }
  }

  float sum = 0.f, sumsq = 0.f;
  #pragma unroll
  for (int j = 0; j < 4; j++){ sum += acc[j]; sumsq += acc[j]*acc[j]; }
  #pragma unroll
  for (int off = 32; off > 0; off >>= 1){
    sum   += __shfl_down(sum, off, 64);
    sumsq += __shfl_down(sumsq, off, 64);
  }
  const int wid = tid >> 6, lane = tid & 63;
  if (lane == 0){ rs[wid] = sum; rq[wid] = sumsq; }
  __syncthreads();
  float ts = 0.f, tq = 0.f;
  #pragma unroll
  for (int i = 0; i < 16; i++){ ts += rs[i]; tq += rq[i]; }
  const float mean = ts * (1.f/4096.f);
  const float var  = tq * (1.f/4096.f) - mean*mean;
  const float rinv = rsqrtf(var + 1e-5f);

  *(ushort4*)(ybn + (size_t)c * NSP + tid*4) =
      pk4((acc[0]-mean)*rinv, (acc[1]-mean)*rinv, (acc[2]-mean)*rinv, (acc[3]-mean)*rinv);
}

// ---------------------------------------------------------------------------
// Kernel 2: fused transpose + MFMA QKV GEMM. Reads ybn[c][n] directly:
// stages the 64-n Y-tile [n][c] in LDS (in-block transpose), W bf16 in LDS.
// Block: 64 o x 64 n, 4 waves. Epilogue operand order per output ->
// contiguous ushort4 stores. q pre-scaled by log2(e)/sqrt(hd).
// ---------------------------------------------------------------------------
__global__ __launch_bounds__(256) void k_qkv(
    const float* __restrict__ wqkv,
    const float* __restrict__ bqkv,
    const unsigned short* __restrict__ ybn,
    unsigned short* __restrict__ qb, unsigned short* __restrict__ kb,
    unsigned short* __restrict__ vbt)
{
  __shared__ unsigned short Wb[64][264];
  __shared__ unsigned short Ys[64][264];   // [n_local][c]
  __shared__ float bsh[64];
  const int tid = threadIdx.x;
  const int o0 = blockIdx.y * 64;
  const int n0 = blockIdx.x * 64;
  {
    const int row = tid & 63, part = tid >> 6;
    const float* src = wqkv + (size_t)(o0 + row) * 256 + part * 64;
    unsigned short* dst = &Wb[row][part*64];
    #pragma unroll
    for (int j = 0; j < 8; j++){
      const float4 a = ((const float4*)src)[2*j];
      const float4 b = ((const float4*)src)[2*j+1];
      *(ushort4*)&dst[j*8]     = pk4(a.x, a.y, a.z, a.w);
      *(ushort4*)&dst[j*8 + 4] = pk4(b.x, b.y, b.z, b.w);
    }
    if (tid < 64) bsh[tid] = bqkv[o0 + tid];
  }
  { // transpose-stage Y: 256 c-rows x 64 n, ushort4 loads -> 4 scalar writes
    const int cl = tid >> 4, n4 = (tid & 15) * 4;
    #pragma unroll
    for (int i = 0; i < 16; i++){
      const int c = cl * 16 + i;
      const ushort4 v = *(const ushort4*)(ybn + (size_t)c * NSP + n0 + n4);
      Ys[n4+0][c] = v.x; Ys[n4+1][c] = v.y; Ys[n4+2][c] = v.z; Ys[n4+3][c] = v.w;
    }
  }
  __syncthreads();

  const int w = tid >> 6, lane = tid & 63, quad = lane >> 4, cc = lane & 15;
  const int nbase = n0 + w*16;
  const bool isv = (o0 >= 512);
  f32x4 acc[4] = {};

  #pragma unroll
  for (int k = 0; k < 8; k++){
    const bf16x8 y0 = *(const bf16x8*)&Ys[w*16 + cc][k*32 + quad*8];
    #pragma unroll
    for (int os = 0; os < 4; os++){
      const bf16x8 wf = *(const bf16x8*)&Wb[os*16 + cc][k*32 + quad*8];
      if (!isv) acc[os] = __builtin_amdgcn_mfma_f32_16x16x32_bf16(wf, y0, acc[os], 0, 0, 0);
      else      acc[os] = __builtin_amdgcn_mfma_f32_16x16x32_bf16(y0, wf, acc[os], 0, 0, 0);
    }
  }

  if (!isv){
    // D rows = o (lane: 4 consecutive dd), col = n = cc
    #pragma unroll
    for (int os = 0; os < 4; os++){
      const int obase = o0 + os*16 + quad*4;
      const int g = obase >> 8, hh = (obase >> 5) & 7, dd0 = obase & 31;
      const int n = nbase + cc;
      unsigned short* dst = (g == 0) ? qb : kb;
      const float sc = (g == 0) ? QSC2 : 1.f;
      const int bb = os*16 + quad*4;
      *(ushort4*)&dst[((size_t)hh * NSP + n) * 32 + dd0] =
          pk4((acc[os][0] + bsh[bb+0]) * sc, (acc[os][1] + bsh[bb+1]) * sc,
              (acc[os][2] + bsh[bb+2]) * sc, (acc[os][3] + bsh[bb+3]) * sc);
    }
  } else {
    // D rows = n (lane: 4 consecutive n), col = o = cc
    #pragma unroll
    for (int os = 0; os < 4; os++){
      const int orow = o0 - 512 + os*16 + cc;   // = h*32+dd
      const float bias = bsh[os*16 + cc];
      const int n4 = nbase + quad*4;
      *(ushort4*)&vbt[(size_t)orow * NSP + n4] =
          pk4(acc[os][0] + bias, acc[os][1] + bias, acc[os][2] + bias, acc[os][3] + bias);
    }
  }
}

// ---------------------------------------------------------------------------
// Kernel 3: MFMA flash attention on 32x32x16. Block = 4 waves x 32 q-rows
// sharing one 64-wide K/V LDS tile; z-split nz. Softmax+PV per 32-kcol half
// -> pst halved -> LDS 19.9 KB -> 8 blocks/CU; nz=8 gives 2048 blocks so all
// 8 are resident (32 waves/CU). Raw v_exp, per-lane lsum.
// ---------------------------------------------------------------------------
__global__ __launch_bounds__(256) void k_attn(
    const unsigned short* __restrict__ qb,
    const unsigned short* __restrict__ kb,
    const unsigned short* __restrict__ vbt,
    unsigned short* __restrict__ opb, float* __restrict__ lp, int ktlen)
{
  const int h = blockIdx.y, q0 = blockIdx.x * 128, z = blockIdx.z;
  const int tid = threadIdx.x;
  const int w = tid >> 6, l = tid & 63;
  const int lq = l & 31, lb = l >> 5;

  __shared__ unsigned short ks [64][40];    // K tile [kcol][d]        5120 B
  __shared__ unsigned short vsT[32][72];    // V^T tile [d][kcol]      4608 B
  __shared__ unsigned short pst[128][40];   // P^T [q_local][32 kcols] 10240 B

  const int qg = q0 + w*32 + lq;
  const bf16x8 qf0 = *(const bf16x8*)(qb + ((size_t)(h*NSP + qg))*32 + lb*8);       // d 0..15
  const bf16x8 qf1 = *(const bf16x8*)(qb + ((size_t)(h*NSP + qg))*32 + 16 + lb*8);  // d 16..31
  const unsigned short* kbase = kb  + (size_t)h * NSP * 32;
  const unsigned short* vbase = vbt + (size_t)h * 32 * NSP;

  f32x16 oacc = {};
  float lsum = 0.f;

  const int kt0 = z * ktlen;
  const int krow = tid >> 2, kseg = (tid & 3) * 8;   // 64 rows x 4 x 16B
  const int vrow = tid >> 3, vseg = (tid & 7) * 8;   // 32 rows x 8 x 16B
  const int iters = ktlen >> 6;

  for (int it = 0; it < iters; it++){
    const int kt = kt0 + it * 64;
    { // stage K (64x32) and V^T (32x64): 16B/thread each
      *(uint4*)&ks[krow][kseg]  = *(const uint4*)(kbase + (size_t)(kt + krow) * 32 + kseg);
      *(uint4*)&vsT[vrow][vseg] = *(const uint4*)(vbase + (size_t)vrow * NSP + kt + vseg);
    }
    __syncthreads();

    // per 32-kcol half: S^T (2 MFMA over d-halves) -> exp -> pst -> PV
    #pragma unroll
    for (int t2 = 0; t2 < 2; t2++){
      const bf16x8 af0 = *(const bf16x8*)&ks[t2*32 + lq][lb*8];
      const bf16x8 af1 = *(const bf16x8*)&ks[t2*32 + lq][16 + lb*8];
      f32x16 sa = {};
      sa = __builtin_amdgcn_mfma_f32_32x32x16_bf16(af0, qf0, sa, 0, 0, 0);
      sa = __builtin_amdgcn_mfma_f32_32x32x16_bf16(af1, qf1, sa, 0, 0, 0);
      // lane holds q=lq, kcol-local = (reg&3) + 8*(reg>>2) + 4*lb
      #pragma unroll
      for (int g = 0; g < 4; g++){
        const float p0 = __builtin_amdgcn_exp2f(sa[g*4+0]);
        const float p1 = __builtin_amdgcn_exp2f(sa[g*4+1]);
        const float p2 = __builtin_amdgcn_exp2f(sa[g*4+2]);
        const float p3 = __builtin_amdgcn_exp2f(sa[g*4+3]);
        lsum += (p0 + p1) + (p2 + p3);
        *(ushort4*)&pst[w*32 + lq][g*8 + lb*4] = pk4(p0, p1, p2, p3);
      }
      // O^T += V^T * P^T for this half: 2 k-chunks of 16
      #pragma unroll
      for (int ck = 0; ck < 2; ck++){
        const bf16x8 vf = *(const bf16x8*)&vsT[lq]       [t2*32 + ck*16 + lb*8];
        const bf16x8 pf = *(const bf16x8*)&pst[w*32 + lq][ck*16 + lb*8];
        oacc = __builtin_amdgcn_mfma_f32_32x32x16_bf16(vf, pf, oacc, 0, 0, 0);
      }
    }
    __syncthreads();
  }

  lsum += __shfl_xor(lsum, 32, 64);   // combine lb halves for same q

  // O^T C-layout: q = lq, d = (reg&3) + 8*(reg>>2) + 4*lb -> bf16 partials
  unsigned short* dst = opb + ((size_t)z * NSP + qg) * 256 + h*32;
  #pragma unroll
  for (int g = 0; g < 4; g++){
    *(ushort4*)(dst + g*8 + lb*4) =
        pk4(oacc[g*4+0], oacc[g*4+1], oacc[g*4+2], oacc[g*4+3]);
  }
  if (lb == 0) lp[((size_t)z * 8 + h) * NSP + qg] = lsum;
}

// ---------------------------------------------------------------------------
// Kernel 4: fused combine + output projection over nz bf16 splits.
// Block: 32 o x 64 n, grid (64,8) = 512 blocks. Swapped operands:
// lane owns 4 consecutive n -> float4 stores.
// ---------------------------------------------------------------------------
__global__ __launch_bounds__(256) void k_proj(
    const float* __restrict__ wproj,
    const float* __restrict__ bproj,
    const unsigned short* __restrict__ opb,
    const float* __restrict__ lp,
    float* __restrict__ out, int nz)
{
  __shared__ unsigned short Wb[32][264];
  const int tid = threadIdx.x;
  const int o0 = blockIdx.y * 32;
  const int n0 = blockIdx.x * 64;
  {
    const int row = tid & 31, part = tid >> 5;   // 8 parts x 32 floats
    const float* src = wproj + (size_t)(o0 + row) * 256 + part * 32;
    unsigned short* dst = &Wb[row][part*32];
    #pragma unroll
    for (int j = 0; j < 4; j++){
      const float4 a = ((const float4*)src)[2*j];
      const float4 b = ((const float4*)src)[2*j+1];
      *(ushort4*)&dst[j*8]     = pk4(a.x, a.y, a.z, a.w);
      *(ushort4*)&dst[j*8 + 4] = pk4(b.x, b.y, b.z, b.w);
    }
  }
  __syncthreads();

  const int w = tid >> 6, lane = tid & 63, quad = lane >> 4, cc = lane & 15;
  const int nbase = n0 + w*16;
  const int nr = nbase + cc;
  f32x4 acc[2] = {};

  #pragma unroll
  for (int k = 0; k < 8; k++){       // k = c-chunk = head index
    float lt = 0.f;
    float s[8] = {};
    for (int z = 0; z < nz; z++){
      lt += lp[((size_t)z*8 + k) * NSP + nr];
      union { uint4 q; unsigned short u[8]; } v;
      v.q = *(const uint4*)(opb + ((size_t)z * NSP + nr) * 256 + k*32 + quad*8);
      #pragma unroll
      for (int j = 0; j < 8; j++) s[j] += bfu2f(v.u[j]);
    }
    const float r = 1.f / lt;
    union { bf16x8 v; ushort4 u[2]; } yb;
    yb.u[0] = pk4(s[0]*r, s[1]*r, s[2]*r, s[3]*r);
    yb.u[1] = pk4(s[4]*r, s[5]*r, s[6]*r, s[7]*r);
    #pragma unroll
    for (int os = 0; os < 2; os++){
      const bf16x8 wf = *(const bf16x8*)&Wb[os*16 + cc][k*32 + quad*8];
      acc[os] = __builtin_amdgcn_mfma_f32_16x16x32_bf16(yb.v, wf, acc[os], 0, 0, 0);
    }
  }

  // D rows = n (lane: 4 consecutive n), col = o = cc
  #pragma unroll
  for (int os = 0; os < 2; os++){
    const int o = o0 + os*16 + cc;
    const float bias = bproj[o];
    const int n4 = nbase + quad*4;
    *(float4*)&out[(size_t)o * NSP + n4] =
        make_float4(acc[os][0] + bias, acc[os][1] + bias,
                    acc[os][2] + bias, acc[os][3] + bias);
  }
}

// ---------------------------------------------------------------------------
extern "C" void kernel_launch(void* const* d_in, const int* in_sizes, int n_in,
                              void* d_out, int out_size, void* d_ws, size_t ws_size,
                              hipStream_t stream) {
  (void)in_sizes; (void)n_in; (void)out_size;
  const float* x     = (const float*)d_in[0];
  const float* wdw   = (const float*)d_in[1];
  const float* bdw   = (const float*)d_in[2];  (void)bdw; // cancels under InstanceNorm
  const float* wqkv  = (const float*)d_in[3];
  const float* bqkv  = (const float*)d_in[4];
  const float* wproj = (const float*)d_in[5];
  const float* bproj = (const float*)d_in[6];
  float* out = (float*)d_out;

  // z-split depth: 8 (2048 attn blocks = 8/CU) if ws allows; else 4 / 2.
  const int nz = (ws_size >= ((size_t)25 << 20)) ? 8
               : (ws_size >= ((size_t)16 << 20)) ? 4 : 2;
  const int ktlen = NSP / nz;

  char* ws = (char*)d_ws;
  const size_t opB = (size_t)nz << 21;                    // nz * 2 MB
  unsigned short* opb = (unsigned short*)ws;              // [nz][n][256] bf16
  unsigned short* ybn = (unsigned short*)ws;              // 2 MB (dead before opb written)
  unsigned short* qb  = (unsigned short*)(ws + opB);      // 2 MB bf16 [h][n][32]
  unsigned short* kb  = (unsigned short*)(ws + opB + (2<<20));
  unsigned short* vbt = (unsigned short*)(ws + opB + (4<<20));
  float*          lp  = (float*)(ws + opB + (6<<20));     // nz*128 KB [z][h][n]

  k_dwconv <<<dim3(256),        dim3(1024), 0, stream>>>(x, wdw, ybn);
  k_qkv    <<<dim3(64, 12),     dim3(256),  0, stream>>>(wqkv, bqkv, ybn, qb, kb, vbt);
  k_attn   <<<dim3(32, 8, nz),  dim3(256),  0, stream>>>(qb, kb, vbt, opb, lp, ktlen);
  k_proj   <<<dim3(64, 8),      dim3(256),  0, stream>>>(wproj, bproj, opb, lp, out, nz);
}

// Round 14
// 138.239 us; speedup vs baseline: 2.8626x; 1.0758x over previous
//
#include <hip/hip_runtime.h>
#include <hip/hip_bf16.h>

#define NSP 4096   // spatial points = 16*16*16
#define QSC2 0.25503486f   // log2(e)/sqrt(32): folded so softmax uses exp2

typedef __attribute__((ext_vector_type(8))) short bf16x8;
typedef __attribute__((ext_vector_type(4))) float f32x4;
typedef __attribute__((ext_vector_type(16))) float f32x16;

__device__ __forceinline__ unsigned short f2bf(float f){
  union{float f;unsigned int u;}c; c.f=f;
  unsigned int r = c.u + 0x7fffu + ((c.u>>16)&1u);
  return (unsigned short)(r>>16);
}
__device__ __forceinline__ unsigned int pk2(float a, float b){
  __hip_bfloat162 p = __float22bfloat162_rn(make_float2(a, b));
  unsigned int r; __builtin_memcpy(&r, &p, 4); return r;
}
__device__ __forceinline__ ushort4 pk4(float a, float b, float c, float d){
  union { ushort4 u4; uint2 u2; } u;
  u.u2.x = pk2(a, b); u.u2.y = pk2(c, d);
  return u.u4;
}
__device__ __forceinline__ float bfu2f(unsigned short u){
  union { unsigned int i; float f; } c; c.i = ((unsigned int)u) << 16; return c.f;
}

// ---------------------------------------------------------------------------
// Kernel 1: depthwise 3x3x3 conv + InstanceNorm -> normalized bf16 ybn[c][n].
// (b_dw dropped: cancels under InstanceNorm.) One block per channel, 1024
// threads, each owns a 4-wide d-strip.
// ---------------------------------------------------------------------------
__global__ __launch_bounds__(1024) void k_dwconv(
    const float* __restrict__ x,
    const float* __restrict__ wdw,
    unsigned short* __restrict__ ybn)
{
  const int c = blockIdx.x;
  const int tid = threadIdx.x;
  __shared__ float xs[4096];
  __shared__ float wsh[27];
  __shared__ float rs[16], rq[16];

  const float* xc = x + (size_t)c * NSP;
  *(float4*)&xs[tid*4] = ((const float4*)xc)[tid];
  if (tid < 27) wsh[tid] = wdw[c*27 + tid];
  __syncthreads();

  // strip: h = t>>6, w = (t>>2)&15, d0 = (t&3)*4
  const int h = tid >> 6, w = (tid >> 2) & 15, d0 = (tid & 3) * 4;
  float acc[4] = {};
  #pragma unroll
  for (int kh = 0; kh < 3; kh++){
    const int hh = h + kh - 1;
    if ((unsigned)hh >= 16u) continue;
    #pragma unroll
    for (int kw = 0; kw < 3; kw++){
      const int ww = w + kw - 1;
      if ((unsigned)ww >= 16u) continue;
      const float* rowp = &xs[((hh << 4) + ww) << 4];
      float win[6];
      const float4 c0 = *(const float4*)&rowp[d0];
      win[1] = c0.x; win[2] = c0.y; win[3] = c0.z; win[4] = c0.w;
      win[0] = d0        ? rowp[d0 - 1] : 0.f;   // global d = d0-1
      win[5] = (d0 < 12) ? rowp[d0 + 4] : 0.f;   // global d = d0+4
      #pragma unroll
      for (int kd = 0; kd < 3; kd++){
        const float wv = wsh[kh*9 + kw*3 + kd];
        #pragma unroll
        for (int j = 0; j < 4; j++) acc[j] += wv * win[j + kd];
      }
    }
  }

  float sum = 0.f, sumsq = 0.f;
  #pragma unroll
  for (int j = 0; j < 4; j++){ sum += acc[j]; sumsq += acc[j]*acc[j]; }
  #pragma unroll
  for (int off = 32; off > 0; off >>= 1){
    sum   += __shfl_down(sum, off, 64);
    sumsq += __shfl_down(sumsq, off, 64);
  }
  const int wid = tid >> 6, lane = tid & 63;
  if (lane == 0){ rs[wid] = sum; rq[wid] = sumsq; }
  __syncthreads();
  float ts = 0.f, tq = 0.f;
  #pragma unroll
  for (int i = 0; i < 16; i++){ ts += rs[i]; tq += rq[i]; }
  const float mean = ts * (1.f/4096.f);
  const float var  = tq * (1.f/4096.f) - mean*mean;
  const float rinv = rsqrtf(var + 1e-5f);

  *(ushort4*)(ybn + (size_t)c * NSP + tid*4) =
      pk4((acc[0]-mean)*rinv, (acc[1]-mean)*rinv, (acc[2]-mean)*rinv, (acc[3]-mean)*rinv);
}

// ---------------------------------------------------------------------------
// Kernel 2: fused transpose + MFMA QKV GEMM. Reads ybn[c][n] directly:
// stages the 64-n Y-tile [n][c] in LDS (in-block transpose), W bf16 in LDS.
// Block: 64 o x 64 n, 4 waves. Epilogue operand order per output ->
// contiguous ushort4 stores. q pre-scaled by log2(e)/sqrt(hd).
// ---------------------------------------------------------------------------
__global__ __launch_bounds__(256) void k_qkv(
    const float* __restrict__ wqkv,
    const float* __restrict__ bqkv,
    const unsigned short* __restrict__ ybn,
    unsigned short* __restrict__ qb, unsigned short* __restrict__ kb,
    unsigned short* __restrict__ vbt)
{
  __shared__ unsigned short Wb[64][264];
  __shared__ unsigned short Ys[64][264];   // [n_local][c]
  __shared__ float bsh[64];
  const int tid = threadIdx.x;
  const int o0 = blockIdx.y * 64;
  const int n0 = blockIdx.x * 64;
  {
    const int row = tid & 63, part = tid >> 6;
    const float* src = wqkv + (size_t)(o0 + row) * 256 + part * 64;
    unsigned short* dst = &Wb[row][part*64];
    #pragma unroll
    for (int j = 0; j < 8; j++){
      const float4 a = ((const float4*)src)[2*j];
      const float4 b = ((const float4*)src)[2*j+1];
      *(ushort4*)&dst[j*8]     = pk4(a.x, a.y, a.z, a.w);
      *(ushort4*)&dst[j*8 + 4] = pk4(b.x, b.y, b.z, b.w);
    }
    if (tid < 64) bsh[tid] = bqkv[o0 + tid];
  }
  { // transpose-stage Y: 256 c-rows x 64 n, ushort4 loads -> 4 scalar writes
    const int cl = tid >> 4, n4 = (tid & 15) * 4;
    #pragma unroll
    for (int i = 0; i < 16; i++){
      const int c = cl * 16 + i;
      const ushort4 v = *(const ushort4*)(ybn + (size_t)c * NSP + n0 + n4);
      Ys[n4+0][c] = v.x; Ys[n4+1][c] = v.y; Ys[n4+2][c] = v.z; Ys[n4+3][c] = v.w;
    }
  }
  __syncthreads();

  const int w = tid >> 6, lane = tid & 63, quad = lane >> 4, cc = lane & 15;
  const int nbase = n0 + w*16;
  const bool isv = (o0 >= 512);
  f32x4 acc[4] = {};

  #pragma unroll
  for (int k = 0; k < 8; k++){
    const bf16x8 y0 = *(const bf16x8*)&Ys[w*16 + cc][k*32 + quad*8];
    #pragma unroll
    for (int os = 0; os < 4; os++){
      const bf16x8 wf = *(const bf16x8*)&Wb[os*16 + cc][k*32 + quad*8];
      if (!isv) acc[os] = __builtin_amdgcn_mfma_f32_16x16x32_bf16(wf, y0, acc[os], 0, 0, 0);
      else      acc[os] = __builtin_amdgcn_mfma_f32_16x16x32_bf16(y0, wf, acc[os], 0, 0, 0);
    }
  }

  if (!isv){
    // D rows = o (lane: 4 consecutive dd), col = n = cc
    #pragma unroll
    for (int os = 0; os < 4; os++){
      const int obase = o0 + os*16 + quad*4;
      const int g = obase >> 8, hh = (obase >> 5) & 7, dd0 = obase & 31;
      const int n = nbase + cc;
      unsigned short* dst = (g == 0) ? qb : kb;
      const float sc = (g == 0) ? QSC2 : 1.f;
      const int bb = os*16 + quad*4;
      *(ushort4*)&dst[((size_t)hh * NSP + n) * 32 + dd0] =
          pk4((acc[os][0] + bsh[bb+0]) * sc, (acc[os][1] + bsh[bb+1]) * sc,
              (acc[os][2] + bsh[bb+2]) * sc, (acc[os][3] + bsh[bb+3]) * sc);
    }
  } else {
    // D rows = n (lane: 4 consecutive n), col = o = cc
    #pragma unroll
    for (int os = 0; os < 4; os++){
      const int orow = o0 - 512 + os*16 + cc;   // = h*32+dd
      const float bias = bsh[os*16 + cc];
      const int n4 = nbase + quad*4;
      *(ushort4*)&vbt[(size_t)orow * NSP + n4] =
          pk4(acc[os][0] + bias, acc[os][1] + bias, acc[os][2] + bias, acc[os][3] + bias);
    }
  }
}

// ---------------------------------------------------------------------------
// Kernel 3: MFMA flash attention on 32x32x16. Block = 4 waves x 32 q-rows;
// KV tile 128 (halved barrier count vs 64-tile: 2 barriers per 128 kcols).
// pst kept 64-col wide (wave-private rows -> no barrier between halves).
// z-split nz (<=4). Raw v_exp softmax numerator (log2e folded into q).
// LDS 37.4 KB -> 4 blocks/CU, grid 1024 at nz=4.
// ---------------------------------------------------------------------------
__global__ __launch_bounds__(256) void k_attn(
    const unsigned short* __restrict__ qb,
    const unsigned short* __restrict__ kb,
    const unsigned short* __restrict__ vbt,
    unsigned short* __restrict__ opb, float* __restrict__ lp, int ktlen)
{
  const int h = blockIdx.y, q0 = blockIdx.x * 128, z = blockIdx.z;
  const int tid = threadIdx.x;
  const int w = tid >> 6, l = tid & 63;
  const int lq = l & 31, lb = l >> 5;

  __shared__ unsigned short ks [128][40];   // K tile [kcol][d]       10240 B
  __shared__ unsigned short vsT[32][136];   // V^T tile [d][kcol]      8704 B
  __shared__ unsigned short pst[128][72];   // P^T [q][64 kcols]      18432 B

  const int qg = q0 + w*32 + lq;
  const bf16x8 qf0 = *(const bf16x8*)(qb + ((size_t)(h*NSP + qg))*32 + lb*8);       // d 0..15
  const bf16x8 qf1 = *(const bf16x8*)(qb + ((size_t)(h*NSP + qg))*32 + 16 + lb*8);  // d 16..31
  const unsigned short* kbase = kb  + (size_t)h * NSP * 32;
  const unsigned short* vbase = vbt + (size_t)h * 32 * NSP;

  f32x16 oacc = {};
  float lsum = 0.f;

  const int kt0 = z * ktlen;
  const int krow = tid >> 1, kseg = (tid & 1) * 16;   // 128 rows x 2 x 16B
  const int vrow = tid >> 3, vseg = (tid & 7) * 16;   // 32 rows x 8 x 16B
  const int iters = ktlen >> 7;

  for (int it = 0; it < iters; it++){
    const int kt = kt0 + it * 128;
    { // stage K (128x32) and V^T (32x128): 32B/thread each
      const uint4* ksrc = (const uint4*)(kbase + (size_t)(kt + krow) * 32 + kseg);
      const uint4 ka = ksrc[0], kb2 = ksrc[1];
      *(uint4*)&ks[krow][kseg]     = ka;
      *(uint4*)&ks[krow][kseg + 8] = kb2;
      const uint4* vsrc = (const uint4*)(vbase + (size_t)vrow * NSP + kt + vseg);
      const uint4 va = vsrc[0], vb = vsrc[1];
      *(uint4*)&vsT[vrow][vseg]     = va;
      *(uint4*)&vsT[vrow][vseg + 8] = vb;
    }
    __syncthreads();

    // two 64-col halves; pst reused per half (wave-private rows)
    #pragma unroll
    for (int half = 0; half < 2; half++){
      #pragma unroll
      for (int t2 = 0; t2 < 2; t2++){
        const bf16x8 af0 = *(const bf16x8*)&ks[half*64 + t2*32 + lq][lb*8];
        const bf16x8 af1 = *(const bf16x8*)&ks[half*64 + t2*32 + lq][16 + lb*8];
        f32x16 sa = {};
        sa = __builtin_amdgcn_mfma_f32_32x32x16_bf16(af0, qf0, sa, 0, 0, 0);
        sa = __builtin_amdgcn_mfma_f32_32x32x16_bf16(af1, qf1, sa, 0, 0, 0);
        // lane holds q=lq, kcol-local = t2*32 + (reg&3) + 8*(reg>>2) + 4*lb
        #pragma unroll
        for (int g = 0; g < 4; g++){
          const float p0 = __builtin_amdgcn_exp2f(sa[g*4+0]);
          const float p1 = __builtin_amdgcn_exp2f(sa[g*4+1]);
          const float p2 = __builtin_amdgcn_exp2f(sa[g*4+2]);
          const float p3 = __builtin_amdgcn_exp2f(sa[g*4+3]);
          lsum += (p0 + p1) + (p2 + p3);
          *(ushort4*)&pst[w*32 + lq][t2*32 + g*8 + lb*4] = pk4(p0, p1, p2, p3);
        }
      }
      // O^T += V^T * P^T for this 64-col half: 4 k-chunks of 16
      #pragma unroll
      for (int ck = 0; ck < 4; ck++){
        const bf16x8 vf = *(const bf16x8*)&vsT[lq]       [half*64 + ck*16 + lb*8];
        const bf16x8 pf = *(const bf16x8*)&pst[w*32 + lq][ck*16 + lb*8];
        oacc = __builtin_amdgcn_mfma_f32_32x32x16_bf16(vf, pf, oacc, 0, 0, 0);
      }
    }
    __syncthreads();
  }

  lsum += __shfl_xor(lsum, 32, 64);   // combine lb halves for same q

  // O^T C-layout: q = lq, d = (reg&3) + 8*(reg>>2) + 4*lb -> bf16 partials
  unsigned short* dst = opb + ((size_t)z * NSP + qg) * 256 + h*32;
  #pragma unroll
  for (int g = 0; g < 4; g++){
    *(ushort4*)(dst + g*8 + lb*4) =
        pk4(oacc[g*4+0], oacc[g*4+1], oacc[g*4+2], oacc[g*4+3]);
  }
  if (lb == 0) lp[((size_t)z * 8 + h) * NSP + qg] = lsum;
}

// ---------------------------------------------------------------------------
// Kernel 4: fused combine + output projection over nz bf16 splits.
// Block: 32 o x 64 n, grid (64,8) = 512 blocks. Swapped operands:
// lane owns 4 consecutive n -> float4 stores.
// ---------------------------------------------------------------------------
__global__ __launch_bounds__(256) void k_proj(
    const float* __restrict__ wproj,
    const float* __restrict__ bproj,
    const unsigned short* __restrict__ opb,
    const float* __restrict__ lp,
    float* __restrict__ out, int nz)
{
  __shared__ unsigned short Wb[32][264];
  const int tid = threadIdx.x;
  const int o0 = blockIdx.y * 32;
  const int n0 = blockIdx.x * 64;
  {
    const int row = tid & 31, part = tid >> 5;   // 8 parts x 32 floats
    const float* src = wproj + (size_t)(o0 + row) * 256 + part * 32;
    unsigned short* dst = &Wb[row][part*32];
    #pragma unroll
    for (int j = 0; j < 4; j++){
      const float4 a = ((const float4*)src)[2*j];
      const float4 b = ((const float4*)src)[2*j+1];
      *(ushort4*)&dst[j*8]     = pk4(a.x, a.y, a.z, a.w);
      *(ushort4*)&dst[j*8 + 4] = pk4(b.x, b.y, b.z, b.w);
    }
  }
  __syncthreads();

  const int w = tid >> 6, lane = tid & 63, quad = lane >> 4, cc = lane & 15;
  const int nbase = n0 + w*16;
  const int nr = nbase + cc;
  f32x4 acc[2] = {};

  #pragma unroll
  for (int k = 0; k < 8; k++){       // k = c-chunk = head index
    float lt = 0.f;
    float s[8] = {};
    for (int z = 0; z < nz; z++){
      lt += lp[((size_t)z*8 + k) * NSP + nr];
      union { uint4 q; unsigned short u[8]; } v;
      v.q = *(const uint4*)(opb + ((size_t)z * NSP + nr) * 256 + k*32 + quad*8);
      #pragma unroll
      for (int j = 0; j < 8; j++) s[j] += bfu2f(v.u[j]);
    }
    const float r = 1.f / lt;
    union { bf16x8 v; ushort4 u[2]; } yb;
    yb.u[0] = pk4(s[0]*r, s[1]*r, s[2]*r, s[3]*r);
    yb.u[1] = pk4(s[4]*r, s[5]*r, s[6]*r, s[7]*r);
    #pragma unroll
    for (int os = 0; os < 2; os++){
      const bf16x8 wf = *(const bf16x8*)&Wb[os*16 + cc][k*32 + quad*8];
      acc[os] = __builtin_amdgcn_mfma_f32_16x16x32_bf16(yb.v, wf, acc[os], 0, 0, 0);
    }
  }

  // D rows = n (lane: 4 consecutive n), col = o = cc
  #pragma unroll
  for (int os = 0; os < 2; os++){
    const int o = o0 + os*16 + cc;
    const float bias = bproj[o];
    const int n4 = nbase + quad*4;
    *(float4*)&out[(size_t)o * NSP + n4] =
        make_float4(acc[os][0] + bias, acc[os][1] + bias,
                    acc[os][2] + bias, acc[os][3] + bias);
  }
}

// ---------------------------------------------------------------------------
extern "C" void kernel_launch(void* const* d_in, const int* in_sizes, int n_in,
                              void* d_out, int out_size, void* d_ws, size_t ws_size,
                              hipStream_t stream) {
  (void)in_sizes; (void)n_in; (void)out_size;
  const float* x     = (const float*)d_in[0];
  const float* wdw   = (const float*)d_in[1];
  const float* bdw   = (const float*)d_in[2];  (void)bdw; // cancels under InstanceNorm
  const float* wqkv  = (const float*)d_in[3];
  const float* bqkv  = (const float*)d_in[4];
  const float* wproj = (const float*)d_in[5];
  const float* bproj = (const float*)d_in[6];
  float* out = (float*)d_out;

  // z-split depth: 4 (r13 showed nz=8's partial traffic outweighs occupancy).
  const int nz = (ws_size >= ((size_t)16 << 20)) ? 4 : 2;
  const int ktlen = NSP / nz;   // multiple of 128

  char* ws = (char*)d_ws;
  const size_t opB = (size_t)nz << 21;                    // nz * 2 MB
  unsigned short* opb = (unsigned short*)ws;              // [nz][n][256] bf16
  unsigned short* ybn = (unsigned short*)ws;              // 2 MB (dead before opb written)
  unsigned short* qb  = (unsigned short*)(ws + opB);      // 2 MB bf16 [h][n][32]
  unsigned short* kb  = (unsigned short*)(ws + opB + (2<<20));
  unsigned short* vbt = (unsigned short*)(ws + opB + (4<<20));
  float*          lp  = (float*)(ws + opB + (6<<20));     // nz*128 KB [z][h][n]

  k_dwconv <<<dim3(256),        dim3(1024), 0, stream>>>(x, wdw, ybn);
  k_qkv    <<<dim3(64, 12),     dim3(256),  0, stream>>>(wqkv, bqkv, ybn, qb, kb, vbt);
  k_attn   <<<dim3(32, 8, nz),  dim3(256),  0, stream>>>(qb, kb, vbt, opb, lp, ktlen);
  k_proj   <<<dim3(64, 8),      dim3(256),  0, stream>>>(wproj, bproj, opb, lp, out, nz);
}